// Round 1
// baseline (1354.720 us; speedup 1.0000x reference)
//
#include <hip/hip_runtime.h>

#define CH   128
#define OC   3
#define WDIM 512
#define HW   (512 * 512)
#define HW4  (HW / 4)          // 65536 float4 groups per (b,c) plane

// -------- Kernel 1: compute modulated+demodulated weights w[b,o,c] --------
// grid = B (8), block = CH (128). thread = channel c.
__global__ void modweights_kernel(const float* __restrict__ styles,      // [B, WDIM]
                                  const float* __restrict__ conv_weight, // [OC, CH]
                                  const float* __restrict__ aff_weight,  // [CH, WDIM]
                                  const float* __restrict__ aff_bias,    // [CH]
                                  float* __restrict__ wmod) {            // [B, OC, CH]
    const int b = blockIdx.x;
    const int c = threadIdx.x;
    const float AFF_SCALE  = 0.04419417382415922f;   // 1/sqrt(512)
    const float CONV_SCALE = 0.08838834764831845f;   // 1/sqrt(128)

    // z[b,c] = AFF_SCALE * dot(styles[b,:], aff_weight[c,:]) + aff_bias[c]
    const float4* s4 = (const float4*)(styles + (size_t)b * WDIM);
    const float4* a4 = (const float4*)(aff_weight + (size_t)c * WDIM);
    float acc = 0.0f;
#pragma unroll 4
    for (int k = 0; k < WDIM / 4; ++k) {
        float4 sv = s4[k];
        float4 av = a4[k];
        acc += sv.x * av.x + sv.y * av.y + sv.z * av.z + sv.w * av.w;
    }
    const float z = acc * AFF_SCALE + aff_bias[c];

    float wv[OC];
#pragma unroll
    for (int o = 0; o < OC; ++o)
        wv[o] = conv_weight[o * CH + c] * z * CONV_SCALE;

    // per-(b,o) sum of squares across the 128 channels (LDS tree reduce)
    __shared__ float red[CH];
    float ss[OC];
#pragma unroll
    for (int o = 0; o < OC; ++o) {
        red[c] = wv[o] * wv[o];
        __syncthreads();
        for (int s = CH / 2; s > 0; s >>= 1) {
            if (c < s) red[c] += red[c + s];
            __syncthreads();
        }
        ss[o] = red[0];
        __syncthreads();
    }

#pragma unroll
    for (int o = 0; o < OC; ++o) {
        const float demod = rsqrtf(ss[o] + 1e-8f);
        wmod[((size_t)b * OC + o) * CH + c] = wv[o] * demod;
    }
}

// -------- Kernel 2: out[b,o,hw] = sum_c w[b,o,c] * x[b,c,hw] + bias[o] --------
// One thread per float4 of pixels. 256 blocks per batch sample -> b uniform/block.
__global__ __launch_bounds__(256) void torgb_kernel(const float* __restrict__ x,
                                                    const float* __restrict__ wmod,
                                                    const float* __restrict__ conv_bias,
                                                    float* __restrict__ out) {
    const int b  = blockIdx.x >> 8;                         // 256 blocks per b
    const int p4 = ((blockIdx.x & 255) << 8) + threadIdx.x; // 0..HW4-1

    __shared__ float wsh[OC * CH];
    for (int i = threadIdx.x; i < OC * CH; i += 256)
        wsh[i] = wmod[(size_t)b * OC * CH + i];
    __syncthreads();

    const float4* xb = (const float4*)x + (size_t)b * CH * HW4;
    float4 a0 = make_float4(0.f, 0.f, 0.f, 0.f);
    float4 a1 = a0, a2 = a0;

#pragma unroll 8
    for (int c = 0; c < CH; ++c) {
        const float4 xv = xb[(size_t)c * HW4 + p4];
        const float w0 = wsh[c];
        const float w1 = wsh[CH + c];
        const float w2 = wsh[2 * CH + c];
        a0.x = fmaf(w0, xv.x, a0.x); a0.y = fmaf(w0, xv.y, a0.y);
        a0.z = fmaf(w0, xv.z, a0.z); a0.w = fmaf(w0, xv.w, a0.w);
        a1.x = fmaf(w1, xv.x, a1.x); a1.y = fmaf(w1, xv.y, a1.y);
        a1.z = fmaf(w1, xv.z, a1.z); a1.w = fmaf(w1, xv.w, a1.w);
        a2.x = fmaf(w2, xv.x, a2.x); a2.y = fmaf(w2, xv.y, a2.y);
        a2.z = fmaf(w2, xv.z, a2.z); a2.w = fmaf(w2, xv.w, a2.w);
    }

    const float b0 = conv_bias[0], b1 = conv_bias[1], b2 = conv_bias[2];
    a0.x += b0; a0.y += b0; a0.z += b0; a0.w += b0;
    a1.x += b1; a1.y += b1; a1.z += b1; a1.w += b1;
    a2.x += b2; a2.y += b2; a2.z += b2; a2.w += b2;

    float4* o4 = (float4*)out;
    o4[((size_t)b * OC + 0) * HW4 + p4] = a0;
    o4[((size_t)b * OC + 1) * HW4 + p4] = a1;
    o4[((size_t)b * OC + 2) * HW4 + p4] = a2;
}

extern "C" void kernel_launch(void* const* d_in, const int* in_sizes, int n_in,
                              void* d_out, int out_size, void* d_ws, size_t ws_size,
                              hipStream_t stream) {
    const float* x           = (const float*)d_in[0]; // [8,128,512,512]
    const float* styles      = (const float*)d_in[1]; // [8,512]
    const float* conv_weight = (const float*)d_in[2]; // [3,128]
    const float* conv_bias   = (const float*)d_in[3]; // [3]
    const float* aff_weight  = (const float*)d_in[4]; // [128,512]
    const float* aff_bias    = (const float*)d_in[5]; // [128]
    float* out  = (float*)d_out;                      // [8,3,512,512]
    float* wmod = (float*)d_ws;                       // [8,3,128] scratch (12 KB)

    const int B = 8;
    modweights_kernel<<<B, CH, 0, stream>>>(styles, conv_weight, aff_weight, aff_bias, wmod);
    torgb_kernel<<<B * 256, 256, 0, stream>>>(x, wmod, conv_bias, out);
}

// Round 2
// 1310.818 us; speedup vs baseline: 1.0335x; 1.0335x over previous
//
#include <hip/hip_runtime.h>

#define CH   128
#define OC   3
#define WDIM 512
#define HW   (512 * 512)
#define HW4  (HW / 4)          // 65536 float4 groups per (b,c) plane

typedef float f4 __attribute__((ext_vector_type(4)));

// -------- Kernel 1: compute modulated+demodulated weights w[b,o,c] --------
// grid = B (8), block = CH (128). thread = channel c.
__global__ void modweights_kernel(const float* __restrict__ styles,      // [B, WDIM]
                                  const float* __restrict__ conv_weight, // [OC, CH]
                                  const float* __restrict__ aff_weight,  // [CH, WDIM]
                                  const float* __restrict__ aff_bias,    // [CH]
                                  float* __restrict__ wmod) {            // [B, OC, CH]
    const int b = blockIdx.x;
    const int c = threadIdx.x;
    const float AFF_SCALE  = 0.04419417382415922f;   // 1/sqrt(512)
    const float CONV_SCALE = 0.08838834764831845f;   // 1/sqrt(128)

    const f4* s4 = (const f4*)(styles + (size_t)b * WDIM);
    const f4* a4 = (const f4*)(aff_weight + (size_t)c * WDIM);
    float acc = 0.0f;
#pragma unroll 4
    for (int k = 0; k < WDIM / 4; ++k) {
        f4 sv = s4[k];
        f4 av = a4[k];
        acc += sv.x * av.x + sv.y * av.y + sv.z * av.z + sv.w * av.w;
    }
    const float z = acc * AFF_SCALE + aff_bias[c];

    float wv[OC];
#pragma unroll
    for (int o = 0; o < OC; ++o)
        wv[o] = conv_weight[o * CH + c] * z * CONV_SCALE;

    __shared__ float red[CH];
    float ss[OC];
#pragma unroll
    for (int o = 0; o < OC; ++o) {
        red[c] = wv[o] * wv[o];
        __syncthreads();
        for (int s = CH / 2; s > 0; s >>= 1) {
            if (c < s) red[c] += red[c + s];
            __syncthreads();
        }
        ss[o] = red[0];
        __syncthreads();
    }

#pragma unroll
    for (int o = 0; o < OC; ++o) {
        const float demod = rsqrtf(ss[o] + 1e-8f);
        wmod[((size_t)b * OC + o) * CH + c] = wv[o] * demod;
    }
}

// -------- Kernel 2: out[b,o,hw] = sum_c w[b,o,c] * x[b,c,hw] + bias[o] --------
// Each block covers 512 consecutive float4 groups (8 KB) per channel plane.
// Thread t handles groups base+t and base+t+256 (two coalesced 1KB/wave streams).
// 128 blocks per sample -> grid = 1024. Nontemporal: pure streaming, no reuse.
__global__ __launch_bounds__(256) void torgb_kernel(const float* __restrict__ x,
                                                    const float* __restrict__ wmod,
                                                    const float* __restrict__ conv_bias,
                                                    float* __restrict__ out) {
    const int b   = blockIdx.x >> 7;                 // 128 blocks per sample
    const int blk = blockIdx.x & 127;
    const int g0  = (blk << 9) + threadIdx.x;        // [0, HW4)
    // g1 = g0 + 256

    __shared__ float wsh[OC * CH];
    for (int i = threadIdx.x; i < OC * CH; i += 256)
        wsh[i] = wmod[(size_t)b * OC * CH + i];
    __syncthreads();

    const f4* xb = (const f4*)x + (size_t)b * CH * HW4;

    f4 a00 = (f4)0.f, a01 = (f4)0.f, a02 = (f4)0.f;  // pixel group g0
    f4 a10 = (f4)0.f, a11 = (f4)0.f, a12 = (f4)0.f;  // pixel group g1

#pragma unroll 4
    for (int c = 0; c < CH; ++c) {
        const f4 u = __builtin_nontemporal_load(&xb[(size_t)c * HW4 + g0]);
        const f4 v = __builtin_nontemporal_load(&xb[(size_t)c * HW4 + g0 + 256]);
        const float w0 = wsh[c];
        const float w1 = wsh[CH + c];
        const float w2 = wsh[2 * CH + c];
        a00 += u * w0;  a01 += u * w1;  a02 += u * w2;
        a10 += v * w0;  a11 += v * w1;  a12 += v * w2;
    }

    const float b0 = conv_bias[0], b1 = conv_bias[1], b2 = conv_bias[2];
    a00 += b0; a01 += b1; a02 += b2;
    a10 += b0; a11 += b1; a12 += b2;

    f4* o4 = (f4*)out;
    const size_t ob = (size_t)b * OC * HW4;
    __builtin_nontemporal_store(a00, &o4[ob + 0 * HW4 + g0]);
    __builtin_nontemporal_store(a01, &o4[ob + 1 * HW4 + g0]);
    __builtin_nontemporal_store(a02, &o4[ob + 2 * HW4 + g0]);
    __builtin_nontemporal_store(a10, &o4[ob + 0 * HW4 + g0 + 256]);
    __builtin_nontemporal_store(a11, &o4[ob + 1 * HW4 + g0 + 256]);
    __builtin_nontemporal_store(a12, &o4[ob + 2 * HW4 + g0 + 256]);
}

extern "C" void kernel_launch(void* const* d_in, const int* in_sizes, int n_in,
                              void* d_out, int out_size, void* d_ws, size_t ws_size,
                              hipStream_t stream) {
    const float* x           = (const float*)d_in[0]; // [8,128,512,512]
    const float* styles      = (const float*)d_in[1]; // [8,512]
    const float* conv_weight = (const float*)d_in[2]; // [3,128]
    const float* conv_bias   = (const float*)d_in[3]; // [3]
    const float* aff_weight  = (const float*)d_in[4]; // [128,512]
    const float* aff_bias    = (const float*)d_in[5]; // [128]
    float* out  = (float*)d_out;                      // [8,3,512,512]
    float* wmod = (float*)d_ws;                       // [8,3,128] scratch (12 KB)

    const int B = 8;
    modweights_kernel<<<B, CH, 0, stream>>>(styles, conv_weight, aff_weight, aff_bias, wmod);
    torgb_kernel<<<B * 128, 256, 0, stream>>>(x, wmod, conv_bias, out);
}